// Round 2
// 590.644 us; speedup vs baseline: 1.0631x; 1.0631x over previous
//
#include <hip/hip_runtime.h>

typedef short short8 __attribute__((ext_vector_type(8)));
typedef short short4v __attribute__((ext_vector_type(4)));
typedef float f32x4 __attribute__((ext_vector_type(4)));
typedef unsigned short ushort_t;

#define DEV_INLINE __device__ __forceinline__

constexpr int NSEQ = 512, NRES = 384, CM = 256, CO = 32, CZ = 128;
constexpr float F_LN_EPS = 1e-5f, F_NORM_EPS = 1e-3f;

// workspace layout (bytes)
constexpr size_t WS_LT   = 0;                                  // [12288][512] bf16
constexpr size_t WS_RT   = WS_LT + (size_t)12288 * 512 * 2;    // [12288][512] bf16
constexpr size_t WS_WT   = WS_RT + (size_t)12288 * 512 * 2;    // [128 kc][128 f][8] bf16 (chunk-major)
constexpr size_t WS_NORM = WS_WT + (size_t)128 * 1024 * 2;     // [384][384] f32
constexpr size_t WS_PW   = WS_NORM + (size_t)384 * 384 * 4;    // [64][256] bf16 packed proj weights

DEV_INLINE ushort_t f2bf(float x) {
  union { float f; unsigned u; } v; v.f = x;
  unsigned r = v.u + 0x7FFFu + ((v.u >> 16) & 1u);
  return (ushort_t)(r >> 16);
}

DEV_INLINE short8 pack8(float4 a, float4 b) {
  short8 p;
  p[0] = (short)f2bf(a.x); p[1] = (short)f2bf(a.y);
  p[2] = (short)f2bf(a.z); p[3] = (short)f2bf(a.w);
  p[4] = (short)f2bf(b.x); p[5] = (short)f2bf(b.y);
  p[6] = (short)f2bf(b.z); p[7] = (short)f2bf(b.w);
  return p;
}

// async global->LDS, 16B per lane; lds dest = wave-uniform base + lane*16
DEV_INLINE void async16(const void* g, void* l) {
  __builtin_amdgcn_global_load_lds(
      (const __attribute__((address_space(1))) unsigned*)g,
      (__attribute__((address_space(3))) unsigned*)l, 16, 0, 0);
}

// ---------------------------------------------------------------------------
// Kernel: repack output_w [c][e][f] f32 -> WT2 chunk-major bf16:
// WT2[((k>>3)*128 + f)*8 + (k&7)] = W[k][f], k = c*32+e (contraction index).
// GEMM2 loads B fragments directly from global: a 16-lane group reads
// 256B contiguous (f-major within a k-chunk).
__global__ __launch_bounds__(256) void k_wt(const float* __restrict__ W,
                                            ushort_t* __restrict__ WT2) {
  int tid = blockIdx.x * 256 + threadIdx.x;      // 0..131071
  int k = tid >> 7, f = tid & 127;               // k = ce index 0..1023
  WT2[((size_t)(k >> 3) * 128 + f) * 8 + (k & 7)] = f2bf(W[(size_t)k * CZ + f]);
}

// ---------------------------------------------------------------------------
// Kernel: pack combined projection weights -> PW[64][256] bf16 (frag-linear).
// Row o<32 = left_w[o], row o>=32 = right_w[o-32].
__global__ __launch_bounds__(256) void k_pack(const float* __restrict__ left_w,
                                              const float* __restrict__ right_w,
                                              ushort_t* __restrict__ PW) {
  int id = blockIdx.x * 256 + threadIdx.x;   // 0..2047
  int o = id >> 5, ch = id & 31;             // 64 rows x 32 chunks of 8
  const float* src = (o < 32 ? left_w + (size_t)o * CM
                             : right_w + (size_t)(o - 32) * CM) + ch * 8;
  float4 a = *(const float4*)src, b = *(const float4*)(src + 4);
  *(short8*)&PW[(size_t)o * CM + ch * 8] = pack8(a, b);
}

// ---------------------------------------------------------------------------
// Kernel: norm[b][d] = sum_a mask[a][b]*mask[a][d]
__global__ __launch_bounds__(256) void k_norm(const float* __restrict__ mask,
                                              float* __restrict__ normM) {
  int b = blockIdx.x * 16 + threadIdx.x;
  int d = blockIdx.y * 16 + threadIdx.y;
  float a0 = 0.f, a1 = 0.f, a2 = 0.f, a3 = 0.f;
  for (int a = 0; a < NSEQ; a += 4) {
    a0 += mask[(size_t)(a + 0) * NRES + b] * mask[(size_t)(a + 0) * NRES + d];
    a1 += mask[(size_t)(a + 1) * NRES + b] * mask[(size_t)(a + 1) * NRES + d];
    a2 += mask[(size_t)(a + 2) * NRES + b] * mask[(size_t)(a + 2) * NRES + d];
    a3 += mask[(size_t)(a + 3) * NRES + b] * mask[(size_t)(a + 3) * NRES + d];
  }
  normM[(size_t)b * NRES + d] = (a0 + a1) + (a2 + a3);
}

// ---------------------------------------------------------------------------
// Kernel: LayerNorm + left/right projection (unchanged, verified).
__global__ __launch_bounds__(256) void k_lnproj(
    const float* __restrict__ act, const float* __restrict__ mask,
    const float* __restrict__ ln_w, const float* __restrict__ ln_b,
    const float* __restrict__ left_b, const float* __restrict__ right_b,
    const ushort_t* __restrict__ PW,
    ushort_t* __restrict__ Lt, ushort_t* __restrict__ Rt) {
  __shared__ ushort_t sAct[16 * 256];  // 8 KB: [row a][k], XOR-swizzled 16B chunks

  const int t = threadIdx.x;
  const int a0 = blockIdx.x * 16;
  const int b = blockIdx.y;
  const int r = t >> 4, c = t & 15;  // 16 lanes per row, 16 channels each

  const float4* arow =
      (const float4*)(act + ((size_t)(a0 + r) * NRES + b) * CM + c * 16);
  float4 v[4];
  float s = 0.f, ss = 0.f;
#pragma unroll
  for (int j = 0; j < 4; j++) {
    v[j] = arow[j];
    s += v[j].x + v[j].y + v[j].z + v[j].w;
    ss += v[j].x * v[j].x + v[j].y * v[j].y + v[j].z * v[j].z + v[j].w * v[j].w;
  }
  s += __shfl_xor(s, 1);  s += __shfl_xor(s, 2);
  s += __shfl_xor(s, 4);  s += __shfl_xor(s, 8);
  ss += __shfl_xor(ss, 1); ss += __shfl_xor(ss, 2);
  ss += __shfl_xor(ss, 4); ss += __shfl_xor(ss, 8);
  const float mu = s * (1.f / CM);
  const float rs = rsqrtf(ss * (1.f / CM) - mu * mu + F_LN_EPS);

  const int lane = t & 63, w = t >> 6;
  const int q = lane >> 4, ln = lane & 15;
  short8 bfrag[8];
#pragma unroll
  for (int ks = 0; ks < 8; ks++)
    bfrag[ks] = *(const short8*)&PW[(size_t)(w * 16 + ln) * CM + (ks * 4 + q) * 8];

#pragma unroll
  for (int j = 0; j < 2; j++) {
    int cb = c * 16 + j * 8;
    float4 lw0 = *(const float4*)(ln_w + cb), lw1 = *(const float4*)(ln_w + cb + 4);
    float4 lb0 = *(const float4*)(ln_b + cb), lb1 = *(const float4*)(ln_b + cb + 4);
    float4 x0 = v[2 * j], x1 = v[2 * j + 1], y0, y1;
    y0.x = (x0.x - mu) * rs * lw0.x + lb0.x;
    y0.y = (x0.y - mu) * rs * lw0.y + lb0.y;
    y0.z = (x0.z - mu) * rs * lw0.z + lb0.z;
    y0.w = (x0.w - mu) * rs * lw0.w + lb0.w;
    y1.x = (x1.x - mu) * rs * lw1.x + lb1.x;
    y1.y = (x1.y - mu) * rs * lw1.y + lb1.y;
    y1.z = (x1.z - mu) * rs * lw1.z + lb1.z;
    y1.w = (x1.w - mu) * rs * lw1.w + lb1.w;
    int chunk = c * 2 + j;
    *(short8*)&sAct[r * 256 + ((chunk ^ (r & 7)) * 8)] = pack8(y0, y1);
  }
  __syncthreads();

  f32x4 acc = {0, 0, 0, 0};
#pragma unroll
  for (int ks = 0; ks < 8; ks++) {
    int kc = ks * 4 + q;
    short8 af = *(const short8*)&sAct[ln * 256 + ((kc ^ (ln & 7)) * 8)];
    acc = __builtin_amdgcn_mfma_f32_16x16x32_bf16(af, bfrag[ks], acc, 0, 0, 0);
  }

  const int o = w * 16 + ln;
  float mk[4];
#pragma unroll
  for (int reg = 0; reg < 4; reg++)
    mk[reg] = mask[(size_t)(a0 + q * 4 + reg) * NRES + b];
  float bias = (o < 32) ? left_b[o] : right_b[o - 32];
  ushort_t* dst = (o < 32) ? (Lt + (size_t)(b * 32 + o) * NSEQ)
                           : (Rt + (size_t)(b * 32 + (o - 32)) * NSEQ);
  short4v pk;
#pragma unroll
  for (int reg = 0; reg < 4; reg++)
    pk[reg] = (short)f2bf((acc[reg] + bias) * mk[reg]);
  *(short4v*)&dst[a0 + q * 4] = pk;
}

// ---------------------------------------------------------------------------
// Fused double-GEMM: per block = 4x4 residue pairs.
// GEMM1: P[128 (b,c)][128 (d,e)] = sum_a Lt * Rt (K=512)
//   BK=64, round-0 verified XOR-swizzled layout (pre-swizzled global source +
//   swizzled ds_read), DOUBLE-buffered with the T3 minimum 2-phase pipeline:
//   issue STAGE(kt+1) -> compute tile kt -> vmcnt(0)+barrier. The drain
//   overlaps the compute phase instead of sitting serially before it.
// GEMM2: out[16 pair][128 f] = P2[16][1024] x W; W fragments read directly
//   from global (WT2 chunk-major, L2-resident) -> no staging, no barriers.
__global__ __launch_bounds__(256, 2) void k_opm(
    const ushort_t* __restrict__ Lt, const ushort_t* __restrict__ Rt,
    const ushort_t* __restrict__ WT2, const float* __restrict__ normM,
    const float* __restrict__ out_b, float* __restrict__ out) {
  __shared__ ushort_t smem[32768];   // 64 KB: 2 x (A 16KB + B 16KB)
  ushort_t* sP = smem;               // 32 KB: P2 [16][1024] (overlays buffer 0)

  const int t = threadIdx.x, lane = t & 63, w = t >> 6;
  const int q = lane >> 4, ln = lane & 15;
  const int wm = w & 1, wn = w >> 1;           // 2x2 wave grid
  const int m0 = blockIdx.x * 128, n0 = blockIdx.y * 128;
  const int srow8 = lane >> 3, schunk = lane & 7;  // staging lane map

  // stage one BK=64 tile (A 16KB + B 16KB) into buffer c. 8 async16/thread.
  // LDS dest linear; global source pre-swizzled (gc = schunk ^ (r&7)).
  auto STAGE = [&](int kt, int c) {
    ushort_t* base = smem + c * 16384;
#pragma unroll
    for (int i = 0; i < 4; i++) {
      int rg = w + i * 4;            // 1KB region 0..15
      int r = rg * 8 + srow8;        // tile row 0..127
      int gc = schunk ^ (r & 7);     // swizzle on global side
      async16(Lt + (size_t)(m0 + r) * NSEQ + kt * 64 + gc * 8, (char*)base + rg * 1024);
      async16(Rt + (size_t)(n0 + r) * NSEQ + kt * 64 + gc * 8,
              (char*)base + 16384 + rg * 1024);
    }
  };

  f32x4 acc1[4][4];
#pragma unroll
  for (int i = 0; i < 4; i++)
#pragma unroll
    for (int j = 0; j < 4; j++) acc1[i][j] = {0, 0, 0, 0};

  // ================= GEMM1: K=512, BK=64, 8 tiles, 2-phase pipeline =========
  STAGE(0, 0);
  asm volatile("s_waitcnt vmcnt(0)" ::: "memory");
  __builtin_amdgcn_s_barrier();
#pragma unroll
  for (int kt = 0; kt < 8; kt++) {
    const int cur = kt & 1;
    if (kt + 1 < 8) STAGE(kt + 1, cur ^ 1);  // next-tile loads in flight

    const ushort_t* bA = smem + cur * 16384;
    const ushort_t* bB = bA + 8192;
#pragma unroll
    for (int ks = 0; ks < 2; ks++) {
      int kc = ks * 4 + q;  // chunk within row, 0..7
      short8 af[4], bf[4];
#pragma unroll
      for (int tm = 0; tm < 4; tm++) {
        int rr = wm * 64 + tm * 16 + ln;
        af[tm] = *(const short8*)&bA[rr * 64 + ((kc ^ (rr & 7)) * 8)];
      }
#pragma unroll
      for (int tn = 0; tn < 4; tn++) {
        int rr = wn * 64 + tn * 16 + ln;
        bf[tn] = *(const short8*)&bB[rr * 64 + ((kc ^ (rr & 7)) * 8)];
      }
      __builtin_amdgcn_s_setprio(1);
#pragma unroll
      for (int tm = 0; tm < 4; tm++)
#pragma unroll
        for (int tn = 0; tn < 4; tn++)
          acc1[tm][tn] =
              __builtin_amdgcn_mfma_f32_16x16x32_bf16(af[tm], bf[tn], acc1[tm][tn], 0, 0, 0);
      __builtin_amdgcn_s_setprio(0);
    }
    // next tile staged + all waves done reading cur before it's overwritten
    asm volatile("s_waitcnt vmcnt(0)" ::: "memory");
    __builtin_amdgcn_s_barrier();
  }

  // ============ P -> LDS bf16, layout [pair][ce] swizzled ============
  __syncthreads();
#pragma unroll
  for (int tm = 0; tm < 4; tm++) {
#pragma unroll
    for (int tn = 0; tn < 4; tn++) {
      int pair = (wm * 2 + (tm >> 1)) * 4 + (wn * 2 + (tn >> 1));
      int e = (tn & 1) * 16 + ln;
#pragma unroll
      for (int reg = 0; reg < 4; reg++) {
        int c = (tm & 1) * 16 + q * 4 + reg;
        int ce = c * 32 + e;
        int pos = (ce >> 3) ^ (pair & 7);
        sP[pair * 1024 + pos * 8 + (ce & 7)] = f2bf(acc1[tm][tn][reg]);
      }
    }
  }
  __syncthreads();

  // ================= GEMM2: K=1024, W direct from global, no barriers =======
  f32x4 acc2[2] = {{0, 0, 0, 0}, {0, 0, 0, 0}};
#pragma unroll
  for (int kt = 0; kt < 16; kt++) {
#pragma unroll
    for (int ks = 0; ks < 2; ks++) {
      int c16 = kt * 8 + ks * 4 + q;  // 16B k-chunk 0..127
      short8 af = *(const short8*)&sP[ln * 1024 + ((c16 ^ (ln & 7)) * 8)];
#pragma unroll
      for (int tn = 0; tn < 2; tn++) {
        int fr = w * 32 + tn * 16 + ln;
        short8 bfr = *(const short8*)&WT2[((size_t)c16 * 128 + fr) * 8];
        acc2[tn] = __builtin_amdgcn_mfma_f32_16x16x32_bf16(af, bfr, acc2[tn], 0, 0, 0);
      }
    }
  }

  // ================= epilogue =================
  const int b = blockIdx.x * 4 + q;  // pair = q*4+reg -> bb=q, dd=reg
#pragma unroll
  for (int reg = 0; reg < 4; reg++) {
    int d = blockIdx.y * 4 + reg;
    float inv = 1.f / (F_NORM_EPS + normM[(size_t)b * NRES + d]);
#pragma unroll
    for (int tn = 0; tn < 2; tn++) {
      int f = w * 32 + tn * 16 + ln;
      out[((size_t)b * NRES + d) * CZ + f] = (acc2[tn][reg] + out_b[f]) * inv;
    }
  }
}

// ---------------------------------------------------------------------------
extern "C" void kernel_launch(void* const* d_in, const int* in_sizes, int n_in,
                              void* d_out, int out_size, void* d_ws, size_t ws_size,
                              hipStream_t stream) {
  (void)in_sizes; (void)n_in; (void)out_size; (void)ws_size;
  const float* act      = (const float*)d_in[0];
  const float* mask     = (const float*)d_in[1];
  const float* ln_w     = (const float*)d_in[2];
  const float* ln_b     = (const float*)d_in[3];
  const float* left_w   = (const float*)d_in[4];
  const float* left_b   = (const float*)d_in[5];
  const float* right_w  = (const float*)d_in[6];
  const float* right_b  = (const float*)d_in[7];
  const float* output_w = (const float*)d_in[8];
  const float* output_b = (const float*)d_in[9];
  float* out = (float*)d_out;

  char* ws = (char*)d_ws;
  ushort_t* Lt = (ushort_t*)(ws + WS_LT);
  ushort_t* Rt = (ushort_t*)(ws + WS_RT);
  ushort_t* WT2 = (ushort_t*)(ws + WS_WT);
  float* normM = (float*)(ws + WS_NORM);
  ushort_t* PW = (ushort_t*)(ws + WS_PW);

  hipLaunchKernelGGL(k_pack, dim3(8), dim3(256), 0, stream, left_w, right_w, PW);
  hipLaunchKernelGGL(k_wt, dim3(512), dim3(256), 0, stream, output_w, WT2);
  hipLaunchKernelGGL(k_norm, dim3(24, 24), dim3(16, 16), 0, stream, mask, normM);
  hipLaunchKernelGGL(k_lnproj, dim3(32, 384), dim3(256), 0, stream, act, mask,
                     ln_w, ln_b, left_b, right_b, PW, Lt, Rt);
  hipLaunchKernelGGL(k_opm, dim3(96, 96), dim3(256), 0, stream, Lt, Rt, WT2,
                     normM, output_b, out);
}